// Round 9
// baseline (432.309 us; speedup 1.0000x reference)
//
#include <hip/hip_runtime.h>
#include <math.h>

#define HDIM 1024
#define FDIM 2048   // 2H
#define NEXP 8
#define MTOK 16384  // 8*2048 tokens
#define NSLC 32     // partial-logit slices: 16 bn x 2 wn

// Fragment-major split-bf16 layout for mfma_f32_32x32x16_bf16:
//   af[mt][ks][hl][lane][j]  mt=m>>5 (512), ks=k>>4 (64), hl in {h,l},
//   lane = ((k>>3)&1)*32 + (m&31), j = k&7.   Per (mt): 65536 shorts (128 KB).
//   wf same with nt=n>>5 (64).
// Per (tile, kb=2 ks) the data is 4 KB CONTIGUOUS -> global_load_lds staging
// is wave-uniform-base + lane*16B with no swizzle. Layouts verified r7/r8.

typedef __attribute__((ext_vector_type(8))) short bf16x8;    // 4 VGPRs
typedef __attribute__((ext_vector_type(16))) float f32x16;   // 32x32 acc

__device__ inline unsigned short f2bf_rne(float f) {
    unsigned int u = __float_as_uint(f);
    u = (u + 0x7FFFu + ((u >> 16) & 1u)) >> 16;
    return (unsigned short)u;
}
__device__ inline float bf2f(unsigned short h) {
    unsigned int u = ((unsigned int)h) << 16;
    return __uint_as_float(u);
}

// --- Kernel A: x fp32 -> fragment-major split bf16 af (2 k-passes via LDS) ---
__global__ __launch_bounds__(256) void cvt_x(const float* __restrict__ x,
                                             unsigned short* __restrict__ af)
{
    __shared__ unsigned short hs[16384];  // 32 KB  [ks_local 32][lane 64][j 8]
    __shared__ unsigned short ls[16384];  // 32 KB
    const int mt = blockIdx.x;            // 0..511 (32-row tiles)
    const int m = threadIdx.x & 31;
    const int kc = threadIdx.x >> 5;      // 0..7
    const float* src = x + ((size_t)mt * 32 + m) * HDIM;
    unsigned short* dst = af + (size_t)mt * 65536;

    #pragma unroll
    for (int p = 0; p < 2; p++) {
        #pragma unroll
        for (int i = 0; i < 8; i++) {
            int k_local = kc * 64 + i * 8;          // 0..511
            int k = p * 512 + k_local;
            float v[8];
            *(float4*)(v)     = *(const float4*)(src + k);
            *(float4*)(v + 4) = *(const float4*)(src + k + 4);
            union { unsigned short u[8]; uint4 q; } oh, ol;
            #pragma unroll
            for (int j = 0; j < 8; j++) {
                unsigned short h = f2bf_rne(v[j]);
                oh.u[j] = h;
                ol.u[j] = f2bf_rne(v[j] - bf2f(h));
            }
            int ks_l = k_local >> 4;                // 0..31
            int lane = ((k_local >> 3) & 1) * 32 + m;
            int o = ks_l * 512 + lane * 8;
            *(uint4*)(hs + o) = oh.q;
            *(uint4*)(ls + o) = ol.q;
        }
        __syncthreads();
        unsigned short* dp = dst + p * 32768;
        #pragma unroll
        for (int c = 0; c < 16; c++) {
            int f = c * 2048 + threadIdx.x * 8;
            int ks_l = f >> 10, hl = (f >> 9) & 1, rest = f & 511;
            const unsigned short* s = (hl ? ls : hs) + ks_l * 512 + rest;
            *(uint4*)(dp + f) = *(const uint4*)s;
        }
        __syncthreads();
    }
}

// --- Kernel B: w1 [K][N] fp32 -> fragment-major split bf16 wf ---
__global__ __launch_bounds__(256) void cvt_w1f(const float* __restrict__ w1,
                                               unsigned short* __restrict__ wf)
{
    __shared__ float t[32][33];
    int n0 = blockIdx.x * 32;   // over FDIM
    int k0 = blockIdx.y * 32;   // over HDIM
    int lx = threadIdx.x & 31, ly = threadIdx.x >> 5;  // 32 x 8
    #pragma unroll
    for (int r = 0; r < 32; r += 8)
        t[ly + r][lx] = w1[(size_t)(k0 + ly + r) * FDIM + n0 + lx];
    __syncthreads();
    #pragma unroll
    for (int r = 0; r < 32; r += 8) {
        float v = t[lx][ly + r];
        unsigned short h = f2bf_rne(v);
        unsigned short l = f2bf_rne(v - bf2f(h));
        int n = n0 + ly + r, k = k0 + lx;
        size_t base = ((size_t)(n >> 5) * 64 + (k >> 4)) * 1024;
        int lj = (((k >> 3) & 1) * 32 + (n & 31)) * 8 + (k & 7);
        wf[base + lj] = h;
        wf[base + 512 + lj] = l;
    }
}

// --- Kernel C: split-bf16 GEMM1, 32x32x16, distinct-bytes LDS sharing. ---
// Block 128x128 (4 waves 2x2); wave 64x64 via 2x2 frags; K-step 32 per iter.
// Stage only DISTINCT operands (32 KB/iter) via global_load_lds (halves the
// L2->CU traffic that bounded round 6); waves read frags from LDS.
// Loads for t+1 issue AFTER the sync of iter t -> each sync drains only
// ~775-cyc-old loads (no m97-style fresh-load drain).
__global__ __launch_bounds__(256, 2) void gemm1_mfma(
    const unsigned short* __restrict__ af, const unsigned short* __restrict__ wf,
    const float* __restrict__ b1, const float* __restrict__ w2,
    float* __restrict__ part)
{
    __shared__ __align__(16) short As[2][8192];  // 2 x 16 KB (4 mt x 4 KB)
    __shared__ __align__(16) short Bs[2][8192];  // 2 x 16 KB (4 nt x 4 KB)

    const int tid  = threadIdx.x;
    const int lane = tid & 63;
    const int l31  = lane & 31;
    const int half = lane >> 5;
    const int wave = tid >> 6;
    const int wm   = wave & 1;
    const int wn   = wave >> 1;

    // XCD swizzle: per XCD walk 4 strips x 16 bn x 4 bmo; A hot/XCD ~2 MB,
    // B per bn 512 KB -> fits the 4 MB per-XCD L2.
    const int id = blockIdx.x;                  // 0..2047
    const int xcd = id & 7, seq = id >> 3;      // seq 0..255
    const int strip = seq >> 6;                 // 0..3
    const int bn = (seq >> 2) & 15;
    const int bmo = seq & 3;
    const int bm = strip * 32 + xcd * 4 + bmo;  // 0..127
    const int m0 = bm * 128, n0 = bn * 128;

    // staging: wave w stages A tile (bm*4+w) and B tile (bn*4+w); per iter a
    // 4 KB contiguous chunk each (4 x 16B per thread), lane-contiguous.
    const unsigned short* asrc = af + (size_t)(bm * 4 + wave) * 65536 + lane * 8;
    const unsigned short* bsrc = wf + (size_t)(bn * 4 + wave) * 65536 + lane * 8;

    f32x16 acc[2][2];
    #pragma unroll
    for (int i = 0; i < 2; i++)
        #pragma unroll
        for (int j = 0; j < 2; j++)
            #pragma unroll
            for (int r = 0; r < 16; r++) acc[i][j][r] = 0.f;

    // prologue: stage iter 0 into buf 0
    #pragma unroll
    for (int c = 0; c < 4; c++) {
        __builtin_amdgcn_global_load_lds(
            (const __attribute__((address_space(1))) void*)(asrc + c * 512),
            (__attribute__((address_space(3))) void*)&As[0][wave * 2048 + c * 512],
            16, 0, 0);
        __builtin_amdgcn_global_load_lds(
            (const __attribute__((address_space(1))) void*)(bsrc + c * 512),
            (__attribute__((address_space(3))) void*)&Bs[0][wave * 2048 + c * 512],
            16, 0, 0);
    }

    #pragma unroll 1
    for (int t = 0; t < 32; t++) {
        __syncthreads();  // buf[t&1] staged (loads ~1 full iter old); prior reads done
        if (t + 1 < 32) {
            const int nb = (t + 1) & 1;
            const unsigned short* an = asrc + (t + 1) * 2048;
            const unsigned short* bnp = bsrc + (t + 1) * 2048;
            #pragma unroll
            for (int c = 0; c < 4; c++) {
                __builtin_amdgcn_global_load_lds(
                    (const __attribute__((address_space(1))) void*)(an + c * 512),
                    (__attribute__((address_space(3))) void*)&As[nb][wave * 2048 + c * 512],
                    16, 0, 0);
                __builtin_amdgcn_global_load_lds(
                    (const __attribute__((address_space(1))) void*)(bnp + c * 512),
                    (__attribute__((address_space(3))) void*)&Bs[nb][wave * 2048 + c * 512],
                    16, 0, 0);
            }
        }
        const short* a = As[t & 1];
        const short* b = Bs[t & 1];

        #pragma unroll
        for (int s = 0; s < 2; s++) {
            bf16x8 Ah[2], Al[2], Bh[2], Bl[2];
            #pragma unroll
            for (int i = 0; i < 2; i++) {
                int ao = (2 * wm + i) * 2048 + s * 1024 + lane * 8;
                Ah[i] = *(const bf16x8*)&a[ao];
                Al[i] = *(const bf16x8*)&a[ao + 512];
                int bo = (2 * wn + i) * 2048 + s * 1024 + lane * 8;
                Bh[i] = *(const bf16x8*)&b[bo];
                Bl[i] = *(const bf16x8*)&b[bo + 512];
            }
            // 3 passes x 4 independent MFMAs (reuse distance 4)
            #pragma unroll
            for (int i = 0; i < 2; i++)
                #pragma unroll
                for (int j = 0; j < 2; j++)
                    acc[i][j] = __builtin_amdgcn_mfma_f32_32x32x16_bf16(
                        Ah[i], Bh[j], acc[i][j], 0, 0, 0);
            #pragma unroll
            for (int i = 0; i < 2; i++)
                #pragma unroll
                for (int j = 0; j < 2; j++)
                    acc[i][j] = __builtin_amdgcn_mfma_f32_32x32x16_bf16(
                        Ah[i], Bl[j], acc[i][j], 0, 0, 0);
            #pragma unroll
            for (int i = 0; i < 2; i++)
                #pragma unroll
                for (int j = 0; j < 2; j++)
                    acc[i][j] = __builtin_amdgcn_mfma_f32_32x32x16_bf16(
                        Al[i], Bh[j], acc[i][j], 0, 0, 0);
        }
    }

    // --- epilogue: bias + exact GELU ---
    // C/D 32x32: col(n) = lane&31, row(m) = (r&3) + 8*(r>>2) + 4*(lane>>5)
    #pragma unroll
    for (int j = 0; j < 2; j++) {
        int n = n0 + wn * 64 + j * 32 + l31;
        float bb = b1[n];
        #pragma unroll
        for (int i = 0; i < 2; i++)
            #pragma unroll
            for (int r = 0; r < 16; r++) {
                float v = acc[i][j][r] + bb;
                acc[i][j][r] = 0.5f * v * (1.0f + erff(v * 0.70710678118654752f));
            }
    }

    float w2r[2][8];
    #pragma unroll
    for (int j = 0; j < 2; j++) {
        const float4* p = (const float4*)(w2 + (size_t)(n0 + wn * 64 + j * 32 + l31) * NEXP);
        float4 u = p[0], v = p[1];
        w2r[j][0] = u.x; w2r[j][1] = u.y; w2r[j][2] = u.z; w2r[j][3] = u.w;
        w2r[j][4] = v.x; w2r[j][5] = v.y; w2r[j][6] = v.z; w2r[j][7] = v.w;
    }

    const int sl = bn * 2 + wn;  // partial slice (deterministic)
    #pragma unroll
    for (int e = 0; e < NEXP; e++) {
        float p[2][16];
        #pragma unroll
        for (int i = 0; i < 2; i++)
            #pragma unroll
            for (int r = 0; r < 16; r++)
                p[i][r] = acc[i][0][r] * w2r[0][e] + acc[i][1][r] * w2r[1][e];
        #pragma unroll
        for (int off = 1; off < 32; off <<= 1)
            #pragma unroll
            for (int i = 0; i < 2; i++)
                #pragma unroll
                for (int r = 0; r < 16; r++)
                    p[i][r] += __shfl_xor(p[i][r], off);
        if (l31 == 0) {
            #pragma unroll
            for (int i = 0; i < 2; i++)
                #pragma unroll
                for (int r = 0; r < 16; r++) {
                    int m = m0 + wm * 64 + i * 32 + (r & 3) + 8 * (r >> 2) + 4 * half;
                    part[(size_t)sl * (MTOK * NEXP) + (size_t)m * NEXP + e] = p[i][r];
                }
        }
    }
}

// --- Kernel 2: logits, top-2, softmax, masks; final losses fused via
// last-block-done (device-scope atomics + threadfence). ---
__global__ __launch_bounds__(256) void router_topk(
    const float* __restrict__ part, const float* __restrict__ b2,
    float* __restrict__ out, float* __restrict__ gu, int* __restrict__ gc,
    int* __restrict__ gd)
{
    const int t = blockIdx.x * 256 + threadIdx.x;

    float logit[8];
    #pragma unroll
    for (int e = 0; e < 8; e++) logit[e] = b2[e];
    #pragma unroll
    for (int j = 0; j < NSLC; j++) {
        const float4* p4 = (const float4*)(part + (size_t)j * (MTOK * NEXP) + (size_t)t * NEXP);
        float4 u = p4[0], v = p4[1];
        logit[0] += u.x; logit[1] += u.y; logit[2] += u.z; logit[3] += u.w;
        logit[4] += v.x; logit[5] += v.y; logit[6] += v.z; logit[7] += v.w;
    }

    int i1 = 0; float v1 = logit[0];
    #pragma unroll
    for (int e = 1; e < 8; e++) { if (logit[e] > v1) { v1 = logit[e]; i1 = e; } }
    int i2 = -1; float v2 = -INFINITY;
    #pragma unroll
    for (int e = 0; e < 8; e++) {
        if (e != i1 && logit[e] > v2) { v2 = logit[e]; i2 = e; }
    }
    float ex = expf(v2 - v1);
    float inv = 1.0f / (1.0f + ex);
    float wa = inv, wb = ex * inv;

    float4* o = (float4*)(out + (size_t)t * NEXP);
    o[0] = make_float4(logit[0], logit[1], logit[2], logit[3]);
    o[1] = make_float4(logit[4], logit[5], logit[6], logit[7]);

    float mk[8];
    #pragma unroll
    for (int e = 0; e < 8; e++) mk[e] = 0.0f;
    mk[i1] = wa; mk[i2] = wb;
    float4* om = (float4*)(out + (size_t)(MTOK * NEXP) + (size_t)t * NEXP);
    om[0] = make_float4(mk[0], mk[1], mk[2], mk[3]);
    om[1] = make_float4(mk[4], mk[5], mk[6], mk[7]);

    __shared__ float us[8];
    __shared__ int cs;
    __shared__ int lastf;
    if (threadIdx.x < 8) us[threadIdx.x] = 0.0f;
    if (threadIdx.x == 0) cs = 0;
    __syncthreads();
    atomicAdd(&us[i1], wa);
    atomicAdd(&us[i2], wb);
    int cnt = (wa > 0.0f ? 1 : 0) + (wb > 0.0f ? 1 : 0);
    atomicAdd(&cs, cnt);
    __syncthreads();
    if (threadIdx.x < 8) atomicAdd(&gu[threadIdx.x], us[threadIdx.x]);
    if (threadIdx.x == 0) atomicAdd(gc, cs);
    __threadfence();
    if (threadIdx.x == 0)
        lastf = (atomicAdd(gd, 1) == (int)gridDim.x - 1) ? 1 : 0;
    __syncthreads();
    if (lastf && threadIdx.x == 0) {
        float u[8]; float tot = 0.0f;
        #pragma unroll
        for (int e = 0; e < 8; e++) { u[e] = atomicAdd(&gu[e], 0.0f); tot += u[e]; }
        int c = atomicAdd(gc, 0);
        float lb = 0.0f;
        #pragma unroll
        for (int e = 0; e < 8; e++) {
            float un = u[e] / tot;
            out[2 * MTOK * NEXP + 1 + e] = un;
            float d = un - 0.125f;
            lb += d * d;
        }
        lb *= (1.0f / 8.0f);
        float sp = ((float)c / (float)MTOK) * 0.5f;
        out[2 * MTOK * NEXP] = lb + 0.1f * sp;
    }
}

extern "C" void kernel_launch(void* const* d_in, const int* in_sizes, int n_in,
                              void* d_out, int out_size, void* d_ws, size_t ws_size,
                              hipStream_t stream) {
    const float* x  = (const float*)d_in[0];
    const float* w1 = (const float*)d_in[1];
    const float* b1 = (const float*)d_in[2];
    const float* w2 = (const float*)d_in[3];
    const float* b2 = (const float*)d_in[4];
    float* out = (float*)d_out;

    unsigned short* af = (unsigned short*)d_ws;            // 512*65536*2 B = 64 MiB
    unsigned short* wf = af + (size_t)512 * 65536;         // 64*65536*2 B = 8 MiB
    float* part = (float*)(wf + (size_t)64 * 65536);       // 16 MiB
    float* gu = part + (size_t)NSLC * MTOK * NEXP;         // 8 floats
    int* gc = (int*)(gu + 8);                              // 1 int
    int* gd = gc + 1;                                      // 1 int (done counter)

    hipMemsetAsync(gu, 0, 64, stream);

    cvt_x<<<512, 256, 0, stream>>>(x, af);
    cvt_w1f<<<dim3(FDIM / 32, HDIM / 32), 256, 0, stream>>>(w1, wf);
    gemm1_mfma<<<2048, 256, 0, stream>>>(af, wf, b1, w2, part);
    router_topk<<<MTOK / 256, 256, 0, stream>>>(part, b2, out, gu, gc, gd);
}

// Round 10
// 420.802 us; speedup vs baseline: 1.0273x; 1.0273x over previous
//
#include <hip/hip_runtime.h>
#include <math.h>

#define HDIM 1024
#define FDIM 2048   // 2H
#define NEXP 8
#define MTOK 16384  // 8*2048 tokens
#define NSLC 32     // partial-logit slices: 16 bn x 2 wn

// Fragment-major split-bf16 layout for mfma_f32_32x32x16_bf16:
//   af[mt][ks][hl][lane][j]  mt=m>>5 (512), ks=k>>4 (64), hl in {h,l},
//   lane = ((k>>3)&1)*32 + (m&31), j = k&7.   Per (mt): 65536 shorts (128 KB).
//   wf same with nt=n>>5 (64).  Layouts verified end-to-end r7/r8/r9.

typedef __attribute__((ext_vector_type(8))) short bf16x8;    // 4 VGPRs
typedef __attribute__((ext_vector_type(16))) float f32x16;   // 32x32 acc

__device__ inline unsigned short f2bf_rne(float f) {
    unsigned int u = __float_as_uint(f);
    u = (u + 0x7FFFu + ((u >> 16) & 1u)) >> 16;
    return (unsigned short)u;
}
__device__ inline float bf2f(unsigned short h) {
    unsigned int u = ((unsigned int)h) << 16;
    return __uint_as_float(u);
}

// --- Kernel A: x fp32 -> fragment-major split bf16 af (2 k-passes via LDS) ---
__global__ __launch_bounds__(256) void cvt_x(const float* __restrict__ x,
                                             unsigned short* __restrict__ af)
{
    __shared__ unsigned short hs[16384];  // 32 KB  [ks_local 32][lane 64][j 8]
    __shared__ unsigned short ls[16384];  // 32 KB
    const int mt = blockIdx.x;            // 0..511 (32-row tiles)
    const int m = threadIdx.x & 31;
    const int kc = threadIdx.x >> 5;      // 0..7
    const float* src = x + ((size_t)mt * 32 + m) * HDIM;
    unsigned short* dst = af + (size_t)mt * 65536;

    #pragma unroll
    for (int p = 0; p < 2; p++) {
        #pragma unroll
        for (int i = 0; i < 8; i++) {
            int k_local = kc * 64 + i * 8;          // 0..511
            int k = p * 512 + k_local;
            float v[8];
            *(float4*)(v)     = *(const float4*)(src + k);
            *(float4*)(v + 4) = *(const float4*)(src + k + 4);
            union { unsigned short u[8]; uint4 q; } oh, ol;
            #pragma unroll
            for (int j = 0; j < 8; j++) {
                unsigned short h = f2bf_rne(v[j]);
                oh.u[j] = h;
                ol.u[j] = f2bf_rne(v[j] - bf2f(h));
            }
            int ks_l = k_local >> 4;                // 0..31
            int lane = ((k_local >> 3) & 1) * 32 + m;
            int o = ks_l * 512 + lane * 8;
            *(uint4*)(hs + o) = oh.q;
            *(uint4*)(ls + o) = ol.q;
        }
        __syncthreads();
        unsigned short* dp = dst + p * 32768;
        #pragma unroll
        for (int c = 0; c < 16; c++) {
            int f = c * 2048 + threadIdx.x * 8;
            int ks_l = f >> 10, hl = (f >> 9) & 1, rest = f & 511;
            const unsigned short* s = (hl ? ls : hs) + ks_l * 512 + rest;
            *(uint4*)(dp + f) = *(const uint4*)s;
        }
        __syncthreads();
    }
}

// --- Kernel B: w1 [K][N] fp32 -> fragment-major split bf16 wf ---
__global__ __launch_bounds__(256) void cvt_w1f(const float* __restrict__ w1,
                                               unsigned short* __restrict__ wf)
{
    __shared__ float t[32][33];
    int n0 = blockIdx.x * 32;   // over FDIM
    int k0 = blockIdx.y * 32;   // over HDIM
    int lx = threadIdx.x & 31, ly = threadIdx.x >> 5;  // 32 x 8
    #pragma unroll
    for (int r = 0; r < 32; r += 8)
        t[ly + r][lx] = w1[(size_t)(k0 + ly + r) * FDIM + n0 + lx];
    __syncthreads();
    #pragma unroll
    for (int r = 0; r < 32; r += 8) {
        float v = t[lx][ly + r];
        unsigned short h = f2bf_rne(v);
        unsigned short l = f2bf_rne(v - bf2f(h));
        int n = n0 + ly + r, k = k0 + lx;
        size_t base = ((size_t)(n >> 5) * 64 + (k >> 4)) * 1024;
        int lj = (((k >> 3) & 1) * 32 + (n & 31)) * 8 + (k & 7);
        wf[base + lj] = h;
        wf[base + 512 + lj] = l;
    }
}

// --- Kernel C: split-bf16 GEMM1, 32x32x16, no LDS, no barriers, reg dbuf. ---
// Block 128x128 (4 waves 2x2); wave 64x64 via 2x2 frags of 32x32, k-step 16.
// Uniform SGPR bases + single shared voffset (imm 0/1024/2048/3072 B) keep
// addressing VGPRs ~1.  3 waves/SIMD; acc 64 + operands 64 regs -> no spill.
__global__ __launch_bounds__(256, 3) void gemm1_mfma(
    const unsigned short* __restrict__ af, const unsigned short* __restrict__ wf,
    const float* __restrict__ b1, const float* __restrict__ w2,
    float* __restrict__ part)
{
    const int tid  = threadIdx.x;
    const int lane = tid & 63;
    const int l31  = lane & 31;
    const int half = lane >> 5;
    const int wave = tid >> 6;
    const int wm   = wave & 1;
    const int wn   = wave >> 1;

    // XCD swizzle: per XCD walk 4 strips x 16 bn x 4 bmo; A hot/XCD ~2 MB,
    // B per bn 512 KB -> fits the 4 MB per-XCD L2.
    const int id = blockIdx.x;                  // 0..2047
    const int xcd = id & 7, seq = id >> 3;      // seq 0..255
    const int strip = seq >> 6;                 // 0..3
    const int bn = (seq >> 2) & 15;
    const int bmo = seq & 3;
    const int bm = strip * 32 + xcd * 4 + bmo;  // 0..127
    const int m0 = bm * 128, n0 = bn * 128;

    // UNIFORM tile bases (no lane term -> SGPR pairs)
    const unsigned short* aB0 = af + (size_t)(bm * 4 + wm * 2 + 0) * 65536;
    const unsigned short* aB1 = af + (size_t)(bm * 4 + wm * 2 + 1) * 65536;
    const unsigned short* bB0 = wf + (size_t)(bn * 4 + wn * 2 + 0) * 65536;
    const unsigned short* bB1 = wf + (size_t)(bn * 4 + wn * 2 + 1) * 65536;
    size_t off = (size_t)lane * 8;  // divergent voffset (shorts); += 2048/2 ks

    f32x16 acc[2][2];
    #pragma unroll
    for (int i = 0; i < 2; i++)
        #pragma unroll
        for (int j = 0; j < 2; j++)
            #pragma unroll
            for (int r = 0; r < 16; r++) acc[i][j][r] = 0.f;

    bf16x8 A0[2][2], B0[2][2], A1[2][2], B1[2][2];  // [tile][hl]

    // ks = 0 into buf0 (imm offsets 0 / 1024 B)
    A0[0][0] = *(const bf16x8*)(aB0 + off);
    A0[0][1] = *(const bf16x8*)(aB0 + off + 512);
    A0[1][0] = *(const bf16x8*)(aB1 + off);
    A0[1][1] = *(const bf16x8*)(aB1 + off + 512);
    B0[0][0] = *(const bf16x8*)(bB0 + off);
    B0[0][1] = *(const bf16x8*)(bB0 + off + 512);
    B0[1][0] = *(const bf16x8*)(bB1 + off);
    B0[1][1] = *(const bf16x8*)(bB1 + off + 512);

    #pragma unroll 1
    for (int t = 0; t < 64; t += 2) {
        // prefetch ks = t+1 into buf1 (imm 2048 / 3072 B)
        A1[0][0] = *(const bf16x8*)(aB0 + off + 1024);
        A1[0][1] = *(const bf16x8*)(aB0 + off + 1536);
        A1[1][0] = *(const bf16x8*)(aB1 + off + 1024);
        A1[1][1] = *(const bf16x8*)(aB1 + off + 1536);
        B1[0][0] = *(const bf16x8*)(bB0 + off + 1024);
        B1[0][1] = *(const bf16x8*)(bB0 + off + 1536);
        B1[1][0] = *(const bf16x8*)(bB1 + off + 1024);
        B1[1][1] = *(const bf16x8*)(bB1 + off + 1536);
        // compute ks = t : 3 passes x 4 independent MFMAs
        #pragma unroll
        for (int i = 0; i < 2; i++)
            #pragma unroll
            for (int j = 0; j < 2; j++)
                acc[i][j] = __builtin_amdgcn_mfma_f32_32x32x16_bf16(
                    A0[i][0], B0[j][0], acc[i][j], 0, 0, 0);
        #pragma unroll
        for (int i = 0; i < 2; i++)
            #pragma unroll
            for (int j = 0; j < 2; j++)
                acc[i][j] = __builtin_amdgcn_mfma_f32_32x32x16_bf16(
                    A0[i][0], B0[j][1], acc[i][j], 0, 0, 0);
        #pragma unroll
        for (int i = 0; i < 2; i++)
            #pragma unroll
            for (int j = 0; j < 2; j++)
                acc[i][j] = __builtin_amdgcn_mfma_f32_32x32x16_bf16(
                    A0[i][1], B0[j][0], acc[i][j], 0, 0, 0);
        // advance; prefetch ks = t+2 into buf0 (last iter reads next tile: in-ws)
        off += 2048;
        A0[0][0] = *(const bf16x8*)(aB0 + off);
        A0[0][1] = *(const bf16x8*)(aB0 + off + 512);
        A0[1][0] = *(const bf16x8*)(aB1 + off);
        A0[1][1] = *(const bf16x8*)(aB1 + off + 512);
        B0[0][0] = *(const bf16x8*)(bB0 + off);
        B0[0][1] = *(const bf16x8*)(bB0 + off + 512);
        B0[1][0] = *(const bf16x8*)(bB1 + off);
        B0[1][1] = *(const bf16x8*)(bB1 + off + 512);
        // compute ks = t+1
        #pragma unroll
        for (int i = 0; i < 2; i++)
            #pragma unroll
            for (int j = 0; j < 2; j++)
                acc[i][j] = __builtin_amdgcn_mfma_f32_32x32x16_bf16(
                    A1[i][0], B1[j][0], acc[i][j], 0, 0, 0);
        #pragma unroll
        for (int i = 0; i < 2; i++)
            #pragma unroll
            for (int j = 0; j < 2; j++)
                acc[i][j] = __builtin_amdgcn_mfma_f32_32x32x16_bf16(
                    A1[i][0], B1[j][1], acc[i][j], 0, 0, 0);
        #pragma unroll
        for (int i = 0; i < 2; i++)
            #pragma unroll
            for (int j = 0; j < 2; j++)
                acc[i][j] = __builtin_amdgcn_mfma_f32_32x32x16_bf16(
                    A1[i][1], B1[j][0], acc[i][j], 0, 0, 0);
    }

    // --- epilogue: bias + exact GELU ---
    // C/D 32x32: col(n) = lane&31, row(m) = (r&3) + 8*(r>>2) + 4*(lane>>5)
    #pragma unroll
    for (int j = 0; j < 2; j++) {
        int n = n0 + wn * 64 + j * 32 + l31;
        float bb = b1[n];
        #pragma unroll
        for (int i = 0; i < 2; i++)
            #pragma unroll
            for (int r = 0; r < 16; r++) {
                float v = acc[i][j][r] + bb;
                acc[i][j][r] = 0.5f * v * (1.0f + erff(v * 0.70710678118654752f));
            }
    }

    float w2r[2][8];
    #pragma unroll
    for (int j = 0; j < 2; j++) {
        const float4* p = (const float4*)(w2 + (size_t)(n0 + wn * 64 + j * 32 + l31) * NEXP);
        float4 u = p[0], v = p[1];
        w2r[j][0] = u.x; w2r[j][1] = u.y; w2r[j][2] = u.z; w2r[j][3] = u.w;
        w2r[j][4] = v.x; w2r[j][5] = v.y; w2r[j][6] = v.z; w2r[j][7] = v.w;
    }

    const int sl = bn * 2 + wn;  // partial slice (deterministic)
    #pragma unroll
    for (int e = 0; e < NEXP; e++) {
        float p[2][16];
        #pragma unroll
        for (int i = 0; i < 2; i++)
            #pragma unroll
            for (int r = 0; r < 16; r++)
                p[i][r] = acc[i][0][r] * w2r[0][e] + acc[i][1][r] * w2r[1][e];
        #pragma unroll
        for (int off2 = 1; off2 < 32; off2 <<= 1)
            #pragma unroll
            for (int i = 0; i < 2; i++)
                #pragma unroll
                for (int r = 0; r < 16; r++)
                    p[i][r] += __shfl_xor(p[i][r], off2);
        if (l31 == 0) {
            #pragma unroll
            for (int i = 0; i < 2; i++)
                #pragma unroll
                for (int r = 0; r < 16; r++) {
                    int m = m0 + wm * 64 + i * 32 + (r & 3) + 8 * (r >> 2) + 4 * half;
                    part[(size_t)sl * (MTOK * NEXP) + (size_t)m * NEXP + e] = p[i][r];
                }
        }
    }
}

// --- Kernel 2: logits, top-2, softmax, masks; final losses fused via
// last-block-done (device-scope atomics + threadfence). ---
__global__ __launch_bounds__(256) void router_topk(
    const float* __restrict__ part, const float* __restrict__ b2,
    float* __restrict__ out, float* __restrict__ gu, int* __restrict__ gc,
    int* __restrict__ gd)
{
    const int t = blockIdx.x * 256 + threadIdx.x;

    float logit[8];
    #pragma unroll
    for (int e = 0; e < 8; e++) logit[e] = b2[e];
    #pragma unroll
    for (int j = 0; j < NSLC; j++) {
        const float4* p4 = (const float4*)(part + (size_t)j * (MTOK * NEXP) + (size_t)t * NEXP);
        float4 u = p4[0], v = p4[1];
        logit[0] += u.x; logit[1] += u.y; logit[2] += u.z; logit[3] += u.w;
        logit[4] += v.x; logit[5] += v.y; logit[6] += v.z; logit[7] += v.w;
    }

    int i1 = 0; float v1 = logit[0];
    #pragma unroll
    for (int e = 1; e < 8; e++) { if (logit[e] > v1) { v1 = logit[e]; i1 = e; } }
    int i2 = -1; float v2 = -INFINITY;
    #pragma unroll
    for (int e = 0; e < 8; e++) {
        if (e != i1 && logit[e] > v2) { v2 = logit[e]; i2 = e; }
    }
    float ex = expf(v2 - v1);
    float inv = 1.0f / (1.0f + ex);
    float wa = inv, wb = ex * inv;

    float4* o = (float4*)(out + (size_t)t * NEXP);
    o[0] = make_float4(logit[0], logit[1], logit[2], logit[3]);
    o[1] = make_float4(logit[4], logit[5], logit[6], logit[7]);

    float mk[8];
    #pragma unroll
    for (int e = 0; e < 8; e++) mk[e] = 0.0f;
    mk[i1] = wa; mk[i2] = wb;
    float4* om = (float4*)(out + (size_t)(MTOK * NEXP) + (size_t)t * NEXP);
    om[0] = make_float4(mk[0], mk[1], mk[2], mk[3]);
    om[1] = make_float4(mk[4], mk[5], mk[6], mk[7]);

    __shared__ float us[8];
    __shared__ int cs;
    __shared__ int lastf;
    if (threadIdx.x < 8) us[threadIdx.x] = 0.0f;
    if (threadIdx.x == 0) cs = 0;
    __syncthreads();
    atomicAdd(&us[i1], wa);
    atomicAdd(&us[i2], wb);
    int cnt = (wa > 0.0f ? 1 : 0) + (wb > 0.0f ? 1 : 0);
    atomicAdd(&cs, cnt);
    __syncthreads();
    if (threadIdx.x < 8) atomicAdd(&gu[threadIdx.x], us[threadIdx.x]);
    if (threadIdx.x == 0) atomicAdd(gc, cs);
    __threadfence();
    if (threadIdx.x == 0)
        lastf = (atomicAdd(gd, 1) == (int)gridDim.x - 1) ? 1 : 0;
    __syncthreads();
    if (lastf && threadIdx.x == 0) {
        float u[8]; float tot = 0.0f;
        #pragma unroll
        for (int e = 0; e < 8; e++) { u[e] = atomicAdd(&gu[e], 0.0f); tot += u[e]; }
        int c = atomicAdd(gc, 0);
        float lb = 0.0f;
        #pragma unroll
        for (int e = 0; e < 8; e++) {
            float un = u[e] / tot;
            out[2 * MTOK * NEXP + 1 + e] = un;
            float d = un - 0.125f;
            lb += d * d;
        }
        lb *= (1.0f / 8.0f);
        float sp = ((float)c / (float)MTOK) * 0.5f;
        out[2 * MTOK * NEXP] = lb + 0.1f * sp;
    }
}

extern "C" void kernel_launch(void* const* d_in, const int* in_sizes, int n_in,
                              void* d_out, int out_size, void* d_ws, size_t ws_size,
                              hipStream_t stream) {
    const float* x  = (const float*)d_in[0];
    const float* w1 = (const float*)d_in[1];
    const float* b1 = (const float*)d_in[2];
    const float* w2 = (const float*)d_in[3];
    const float* b2 = (const float*)d_in[4];
    float* out = (float*)d_out;

    unsigned short* af = (unsigned short*)d_ws;            // 512*65536*2 B = 64 MiB
    unsigned short* wf = af + (size_t)512 * 65536;         // 64*65536*2 B = 8 MiB
    float* part = (float*)(wf + (size_t)64 * 65536);       // 16 MiB
    float* gu = part + (size_t)NSLC * MTOK * NEXP;         // 8 floats
    int* gc = (int*)(gu + 8);                              // 1 int
    int* gd = gc + 1;                                      // 1 int (done counter)

    hipMemsetAsync(gu, 0, 64, stream);

    cvt_x<<<512, 256, 0, stream>>>(x, af);
    cvt_w1f<<<dim3(FDIM / 32, HDIM / 32), 256, 0, stream>>>(w1, wf);
    gemm1_mfma<<<2048, 256, 0, stream>>>(af, wf, b1, w2, part);
    router_topk<<<MTOK / 256, 256, 0, stream>>>(part, b2, out, gu, gc, gd);
}